// Round 15
// baseline (50.921 us; speedup 1.0000x reference)
//
#include <hip/hip_runtime.h>

typedef __attribute__((ext_vector_type(8))) short bf16x8;
typedef __attribute__((ext_vector_type(4))) float f32x4;

namespace {
constexpr int UWF = 3, BB = 4, HH = 512, WW = 512;
constexpr int HW = HH * WW;
constexpr int OW = WW * UWF;      // 1536
constexpr int OPL = HH * OW;      // 786432
constexpr float LOG2E = 1.44269504088896340736f;

constexpr int PXB = 128;          // px per block (2 waves x 64 px)
constexpr int XGC = 133;          // staged cols (2+128+2, +1 slack)
constexpr int XGS = 134;          // xg row stride (dwords)
constexpr int ES  = 76;           // e row stride (dwords); slot = ch = kk*3+v

constexpr int W1L_ELEMS = 64 * 32;   // ushort, lane-major conv1 A-frags (weights as A)
constexpr int W2L_ELEMS = 64 * 80;   // ushort, lane-major conv2 B-frags, perm'd chans, *log2e
constexpr int B2L_ELEMS = 64 * 8;    // f32, lane-major b2*log2e (pad to 8)
}

#if __has_builtin(__builtin_amdgcn_exp2f)
#define EXP2(x) __builtin_amdgcn_exp2f(x)   // 1 VALU; hazards compiler-handled (R14: -13%)
#else
#define EXP2(x) exp2f(x)
#endif

__device__ __forceinline__ ushort f2bf(float f) {   // round-half-up
  unsigned u = __builtin_bit_cast(unsigned, f);
  return (ushort)((u + 0x8000u) >> 16);
}

// SWAPPED-conv1 layouts. Lane l = (hi=l>>4, lo=l&15).
// conv1: A = W1:  A[row=ch-sub=lo][k=hi*8+j]; hi<3,j<3 -> w1[ch][hi*3+j]; k==24 -> b1.
//        B = px:  B[k=hi*8+j][col=lo] (built in-kernel from xg).
//        C_t: lane holds ch = t*16+hi*4+r of pixel col=lo  ->  feeds conv2 A directly.
// conv2: A-frag k-slot k = s*32+hi*8+j maps to channel c(k) = (2s+(j>>2))*16 + hi*4 + (j&3);
//        w2 prep uses the same permutation, so the contraction is exact.
__global__ __launch_bounds__(256) void prep_weights(
    const float* __restrict__ w1, const float* __restrict__ b1,
    const float* __restrict__ w2, const float* __restrict__ b2,
    ushort* __restrict__ w1L, ushort* __restrict__ w2L, float* __restrict__ b2L) {
  int idx = blockIdx.x * 256 + threadIdx.x;
  if (idx < W1L_ELEMS) {
    int l = idx >> 5, t = (idx >> 3) & 3, j = idx & 7;
    int hi = l >> 4, lo = l & 15;
    int ch = t * 16 + lo;
    float v = 0.0f;
    if (hi < 3 && j < 3) v = w1[ch * 9 + hi * 3 + j];
    else if (hi == 3 && j == 0) v = b1[ch];
    w1L[idx] = f2bf(v);
  } else if (idx < W1L_ELEMS + W2L_ELEMS) {
    int i2 = idx - W1L_ELEMS;
    int l = i2 / 80, rem = i2 - l * 80, tt = rem >> 3, j = rem & 7;
    int hi = l >> 4, lo = l & 15;
    int t5 = tt >> 1, s = tt & 1;
    int out = t5 * 16 + lo;
    int c = (2 * s + (j >> 2)) * 16 + hi * 4 + (j & 3);   // permuted channel
    w2L[i2] = (out < 75) ? f2bf(w2[out * 64 + c] * LOG2E) : (ushort)0;
  } else if (idx < W1L_ELEMS + W2L_ELEMS + B2L_ELEMS) {
    int i3 = idx - W1L_ELEMS - W2L_ELEMS;
    int l = i3 >> 3, t = i3 & 7;
    int ch = t * 16 + (l & 15);
    b2L[i3] = (t < 5 && ch < 75) ? b2[ch] * LOG2E : 0.0f;
  }
}

// Block = 128 px of one row (2 waves x 64 px; 4 M-tiles of 16 per wave).
// SOFTWARE-PIPELINED: compute(t) -> epilogue(t-1); e_s double-buffered per
// wave so tile t's e-writes are provably disjoint from tile t-1's epilogue
// reads -> compiler interleaves MFMA burst with epilogue FMA chains.
__global__ __launch_bounds__(128, 2) void carafe_mfma(
    const float* __restrict__ x, const ushort* __restrict__ w1L,
    const ushort* __restrict__ w2L, const float* __restrict__ b2L,
    const float* __restrict__ wp, const float* __restrict__ bp,
    float* __restrict__ out) {
  __shared__ __align__(16) float xg_s[5][XGS];          // 2680 B
  __shared__ __align__(16) float e_s[2][2][16 * ES];    // wave x buf x 4864 B

  const int tid = threadIdx.x;
  const int wv = tid >> 6, l = tid & 63;
  const int hi = l >> 4, lo = l & 15;

  const int gpix0 = blockIdx.x * PXB;
  const int b = gpix0 >> 18;
  const int h = (gpix0 >> 9) & (HH - 1);
  const int wb = gpix0 & (WW - 1);

  // fused staging: rows h-2..h+2, cols wb-2..wb+130, channel-mean of x
  const float* xb = x + (size_t)b * 3 * HW;
  for (int i = tid; i < 5 * XGC; i += 128) {
    int r = i / XGC, cc = i - r * XGC;
    int y = h + r - 2, xx = wb + cc - 2;
    float v = 0.0f;
    if ((unsigned)y < (unsigned)HH && (unsigned)xx < (unsigned)WW) {
      const float* p = xb + y * WW + xx;
      v = (p[0] + p[HW] + p[2 * HW]) * (1.0f / 3.0f);
    }
    xg_s[r][cc] = v;
  }

  // lane-major weights: 14 contiguous b128 + 2 f32x4 per lane
  bf16x8 wf1[4], wf2[10];
  const ushort* p1 = w1L + l * 32;
#pragma unroll
  for (int t = 0; t < 4; ++t) wf1[t] = *reinterpret_cast<const bf16x8*>(p1 + t * 8);
  const ushort* p2 = w2L + l * 80;
#pragma unroll
  for (int t = 0; t < 10; ++t) wf2[t] = *reinterpret_cast<const bf16x8*>(p2 + t * 8);
  f32x4 b2a = *reinterpret_cast<const f32x4*>(b2L + l * 8);
  const float b2t4 = b2L[l * 8 + 4];
  const float wps = wp[0], bps = bp[0];
  __syncthreads();

  // prefetch all 4 conv1 B-frags (all xg_s reads under one lgkm window)
  bf16x8 bpx[4];
#pragma unroll
  for (int mt = 0; mt < 4; ++mt) {
    uint4 bw = {0u, 0u, 0u, 0u};
    if (hi < 3) {
      const float* row = &xg_s[1 + hi][wv * 64 + mt * 16 + lo + 1];
      bw.x = ((unsigned)f2bf(row[1]) << 16) | (unsigned)f2bf(row[0]);
      bw.y = (unsigned)f2bf(row[2]);
    } else {
      bw.x = 0x3F80u;
    }
    bpx[mt] = __builtin_bit_cast(bf16x8, bw);
  }

  const int epx = l >> 2, ev = l & 3;

  // epilogue for tile T (compile-time under unroll): reads e_s[wv][T&1]
  auto epilogue = [&](int T) {
    if (ev < 3) {
      const float* erow = e_s[wv][T & 1] + epx * ES + ev;
      const float* nb = &xg_s[0][wv * 64 + T * 16 + epx];
      float n0 = 0.f, n1 = 0.f, d0 = 0.f, d1 = 0.f;
#pragma unroll
      for (int kk = 0; kk < 25; ++kk) {
        int dy = kk / 5, dx = kk - dy * 5;
        float e = erow[3 * kk];
        float nv = nb[dy * XGS + dx];
        if (kk & 1) { n1 = fmaf(e, nv, n1); d1 += e; }
        else        { n0 = fmaf(e, nv, n0); d0 += e; }
      }
      float o = (n0 + n1) * __builtin_amdgcn_rcpf(d0 + d1) * wps + bps;
      int wg = wb + wv * 64 + T * 16 + epx;
      float* op = out + (size_t)b * 3 * OPL + (size_t)h * OW + wg * 3 + ev;
      op[0] = o;
      op[OPL] = o;
      op[2 * (size_t)OPL] = o;
    }
  };

#pragma unroll
  for (int mt = 0; mt < 4; ++mt) {
    float* ew = e_s[wv][mt & 1];

    // conv1 swapped: A = weights, B = pixels. C_t[m=ch-sub][n=px].
    f32x4 zero = {0.f, 0.f, 0.f, 0.f};
    f32x4 h0 = __builtin_amdgcn_mfma_f32_16x16x32_bf16(wf1[0], bpx[mt], zero, 0, 0, 0);
    f32x4 h1 = __builtin_amdgcn_mfma_f32_16x16x32_bf16(wf1[1], bpx[mt], zero, 0, 0, 0);
    f32x4 h2 = __builtin_amdgcn_mfma_f32_16x16x32_bf16(wf1[2], bpx[mt], zero, 0, 0, 0);
    f32x4 h3 = __builtin_amdgcn_mfma_f32_16x16x32_bf16(wf1[3], bpx[mt], zero, 0, 0, 0);

    // ReLU + round-half-up + pack pairs via v_perm: word = (bf(b)<<16)|bf(a)
    auto rp = [](float a, float bb) -> unsigned {
      unsigned ua = __builtin_bit_cast(unsigned, fmaxf(a, 0.0f)) + 0x8000u;
      unsigned ub = __builtin_bit_cast(unsigned, fmaxf(bb, 0.0f)) + 0x8000u;
      return __builtin_amdgcn_perm(ub, ua, 0x07060302u);
    };
    uint4 aw, aw2;
    aw.x  = rp(h0[0], h0[1]); aw.y  = rp(h0[2], h0[3]);
    aw.z  = rp(h1[0], h1[1]); aw.w  = rp(h1[2], h1[3]);
    aw2.x = rp(h2[0], h2[1]); aw2.y = rp(h2[2], h2[3]);
    aw2.z = rp(h3[0], h3[1]); aw2.w = rp(h3[2], h3[3]);
    bf16x8 a2a = __builtin_bit_cast(bf16x8, aw);
    bf16x8 a2b = __builtin_bit_cast(bf16x8, aw2);

    // conv2: A from registers, acc init = b2*log2e, 10 MFMAs, exp -> e LDS
#pragma unroll
    for (int t = 0; t < 5; ++t) {
      float bini = (t < 4) ? b2a[t] : b2t4;
      f32x4 acc = {bini, bini, bini, bini};
      acc = __builtin_amdgcn_mfma_f32_16x16x32_bf16(a2a, wf2[2 * t], acc, 0, 0, 0);
      acc = __builtin_amdgcn_mfma_f32_16x16x32_bf16(a2b, wf2[2 * t + 1], acc, 0, 0, 0);
      int ch = t * 16 + lo;
      bool live = (ch < 75);
#pragma unroll
      for (int r = 0; r < 4; ++r) {
        float e = EXP2(acc[r]);
        if (live) ew[(hi * 4 + r) * ES + ch] = e;   // row = pixel, col = out-ch
      }
    }

    if (mt > 0) epilogue(mt - 1);   // overlap with this tile's compute
  }
  epilogue(3);
}

// Fallback (ws too small; not expected): fused per-pixel fp32 kernel.
__global__ __launch_bounds__(256) void carafe_fused_fallback(
    const float* __restrict__ x,
    const float* __restrict__ w1, const float* __restrict__ b1,
    const float* __restrict__ w2, const float* __restrict__ b2,
    const float* __restrict__ wp, const float* __restrict__ bp,
    float* __restrict__ out) {
  int idx = blockIdx.x * 256 + threadIdx.x;
  int b = idx >> 18;
  int hw = idx & (HW - 1);
  int h = hw >> 9;
  int w = hw & (WW - 1);
  float xw[5][5];
#pragma unroll
  for (int dy = 0; dy < 5; ++dy) {
    int y = h + dy - 2;
#pragma unroll
    for (int dx = 0; dx < 5; ++dx) {
      int xc = w + dx - 2;
      float v = 0.0f;
      if ((unsigned)y < (unsigned)HH && (unsigned)xc < (unsigned)WW) {
        const float* xb = x + (size_t)b * 3 * HW + y * WW + xc;
        v = (xb[0] + xb[HW] + xb[2 * HW]) * (1.0f / 3.0f);
      }
      xw[dy][dx] = v;
    }
  }
  float hb[64];
#pragma unroll
  for (int c = 0; c < 64; ++c) {
    float acc = b1[c];
#pragma unroll
    for (int ky = 0; ky < 3; ++ky)
#pragma unroll
      for (int kx = 0; kx < 3; ++kx)
        acc = fmaf(xw[1 + ky][1 + kx], w1[c * 9 + ky * 3 + kx], acc);
    hb[c] = fmaxf(acc, 0.0f);
  }
  float accv[3] = {0.f, 0.f, 0.f}, sumv[3] = {0.f, 0.f, 0.f};
#pragma unroll
  for (int kk = 0; kk < 25; ++kk) {
    float nv = xw[kk / 5][kk % 5];
#pragma unroll
    for (int v = 0; v < 3; ++v) {
      int ch = kk * 3 + v;
      float lg = b2[ch];
      const float* wrow = w2 + (size_t)ch * 64;
#pragma unroll
      for (int c = 0; c < 64; ++c) lg = fmaf(hb[c], wrow[c], lg);
      float e = __expf(lg);
      sumv[v] += e;
      accv[v] = fmaf(e, nv, accv[v]);
    }
  }
#pragma unroll
  for (int v = 0; v < 3; ++v) {
    float o = (accv[v] / sumv[v]) * wp[0] + bp[0];
    size_t base = (size_t)h * OW + (size_t)w * 3 + v;
#pragma unroll
    for (int c = 0; c < 3; ++c) out[(size_t)(b * 3 + c) * OPL + base] = o;
  }
}

extern "C" void kernel_launch(void* const* d_in, const int* in_sizes, int n_in,
                              void* d_out, int out_size, void* d_ws, size_t ws_size,
                              hipStream_t stream) {
  const float* x  = (const float*)d_in[0];
  const float* w1 = (const float*)d_in[1];
  const float* b1 = (const float*)d_in[2];
  const float* w2 = (const float*)d_in[3];
  const float* b2 = (const float*)d_in[4];
  const float* wp = (const float*)d_in[5];
  const float* bp = (const float*)d_in[6];
  float* out = (float*)d_out;

  const size_t need = (W1L_ELEMS + W2L_ELEMS) * sizeof(ushort) + B2L_ELEMS * sizeof(float);
  if (ws_size >= need) {
    ushort* w1p = (ushort*)d_ws;
    ushort* w2p = w1p + W1L_ELEMS;
    float*  b2p = (float*)(w2p + W2L_ELEMS);
    const int prep_total = W1L_ELEMS + W2L_ELEMS + B2L_ELEMS;
    prep_weights<<<(prep_total + 255) / 256, 256, 0, stream>>>(w1, b1, w2, b2, w1p, w2p, b2p);
    carafe_mfma<<<BB * HW / PXB, 128, 0, stream>>>(x, w1p, w2p, b2p, wp, bp, out);
  } else {
    carafe_fused_fallback<<<BB * HW / 256, 256, 0, stream>>>(x, w1, b1, w2, b2, wp, bp, out);
  }
}

// Round 16
// 47.275 us; speedup vs baseline: 1.0771x; 1.0771x over previous
//
#include <hip/hip_runtime.h>

typedef __attribute__((ext_vector_type(8))) short bf16x8;
typedef __attribute__((ext_vector_type(4))) float f32x4;

namespace {
constexpr int UWF = 3, BB = 4, HH = 512, WW = 512;
constexpr int HW = HH * WW;
constexpr int OW = WW * UWF;      // 1536
constexpr int OPL = HH * OW;      // 786432
constexpr float LOG2E = 1.44269504088896340736f;

constexpr int PXB = 64;           // px per block = 1 wave (fully decoupled, no barrier)
constexpr int XGC = 69;           // staged cols (2+64+2, +1 slack)
constexpr int XGS = 70;           // xg row stride (dwords)
constexpr int ES  = 76;           // e row stride (dwords); slot = ch = kk*3+v

constexpr int W1L_ELEMS = 64 * 32;   // ushort, lane-major conv1 A-frags (weights as A)
constexpr int W2L_ELEMS = 64 * 80;   // ushort, lane-major conv2 B-frags, perm'd chans, *log2e
constexpr int B2L_ELEMS = 64 * 8;    // f32, lane-major b2*log2e (pad to 8)
}

#if __has_builtin(__builtin_amdgcn_exp2f)
#define EXP2(x) __builtin_amdgcn_exp2f(x)   // 1 VALU; hazards compiler-handled (R14: -13%)
#else
#define EXP2(x) exp2f(x)
#endif

__device__ __forceinline__ ushort f2bf(float f) {   // round-half-up
  unsigned u = __builtin_bit_cast(unsigned, f);
  return (ushort)((u + 0x8000u) >> 16);
}

// SWAPPED-conv1 layouts. Lane l = (hi=l>>4, lo=l&15).
// conv1: A = W1:  A[row=ch-sub=lo][k=hi*8+j]; hi<3,j<3 -> w1[ch][hi*3+j]; k==24 -> b1.
//        B = px:  B[k=hi*8+j][col=lo] (built in-kernel from xg).
//        C_t: lane holds ch = t*16+hi*4+r of pixel col=lo  ->  feeds conv2 A directly.
// conv2: A-frag k-slot k = s*32+hi*8+j maps to channel c(k) = (2s+(j>>2))*16 + hi*4 + (j&3);
//        w2 prep uses the same permutation, so the contraction is exact.
__global__ __launch_bounds__(256) void prep_weights(
    const float* __restrict__ w1, const float* __restrict__ b1,
    const float* __restrict__ w2, const float* __restrict__ b2,
    ushort* __restrict__ w1L, ushort* __restrict__ w2L, float* __restrict__ b2L) {
  int idx = blockIdx.x * 256 + threadIdx.x;
  if (idx < W1L_ELEMS) {
    int l = idx >> 5, t = (idx >> 3) & 3, j = idx & 7;
    int hi = l >> 4, lo = l & 15;
    int ch = t * 16 + lo;
    float v = 0.0f;
    if (hi < 3 && j < 3) v = w1[ch * 9 + hi * 3 + j];
    else if (hi == 3 && j == 0) v = b1[ch];
    w1L[idx] = f2bf(v);
  } else if (idx < W1L_ELEMS + W2L_ELEMS) {
    int i2 = idx - W1L_ELEMS;
    int l = i2 / 80, rem = i2 - l * 80, tt = rem >> 3, j = rem & 7;
    int hi = l >> 4, lo = l & 15;
    int t5 = tt >> 1, s = tt & 1;
    int out = t5 * 16 + lo;
    int c = (2 * s + (j >> 2)) * 16 + hi * 4 + (j & 3);   // permuted channel
    w2L[i2] = (out < 75) ? f2bf(w2[out * 64 + c] * LOG2E) : (ushort)0;
  } else if (idx < W1L_ELEMS + W2L_ELEMS + B2L_ELEMS) {
    int i3 = idx - W1L_ELEMS - W2L_ELEMS;
    int l = i3 >> 3, t = i3 & 7;
    int ch = t * 16 + (l & 15);
    b2L[i3] = (t < 5 && ch < 75) ? b2[ch] * LOG2E : 0.0f;
  }
}

// Block = 64 px of one row = ONE WAVE (4 M-tiles of 16). No __syncthreads:
// all LDS is wave-private; compiler inserts the lgkm waits from dataflow.
// Per M-tile: conv1 swapped (4 MFMA, C = ch x px) -> ReLU+pack in registers
// (v_perm) -> conv2 (10 MFMA, acc=b2*log2e) -> v_exp (live only) -> e LDS ->
// epilogue. ~6.3 KB LDS -> many independent waves/CU.
__global__ __launch_bounds__(64, 4) void carafe_mfma(
    const float* __restrict__ x, const ushort* __restrict__ w1L,
    const ushort* __restrict__ w2L, const float* __restrict__ b2L,
    const float* __restrict__ wp, const float* __restrict__ bp,
    float* __restrict__ out) {
  __shared__ __align__(16) float xg_s[5][XGS];   // 1400 B
  __shared__ __align__(16) float e_s[16 * ES];   // 4864 B

  const int l = threadIdx.x;
  const int hi = l >> 4, lo = l & 15;

  const int gpix0 = blockIdx.x * PXB;
  const int b = gpix0 >> 18;
  const int h = (gpix0 >> 9) & (HH - 1);
  const int wb = gpix0 & (WW - 1);

  // fused staging: rows h-2..h+2, cols wb-2..wb+66, channel-mean of x
  const float* xb = x + (size_t)b * 3 * HW;
  for (int i = l; i < 5 * XGC; i += 64) {
    int r = i / XGC, cc = i - r * XGC;
    int y = h + r - 2, xx = wb + cc - 2;
    float v = 0.0f;
    if ((unsigned)y < (unsigned)HH && (unsigned)xx < (unsigned)WW) {
      const float* p = xb + y * WW + xx;
      v = (p[0] + p[HW] + p[2 * HW]) * (1.0f / 3.0f);
    }
    xg_s[r][cc] = v;
  }

  // lane-major weights: 14 contiguous b128 + 2 f32x4 per lane
  bf16x8 wf1[4], wf2[10];
  const ushort* p1 = w1L + l * 32;
#pragma unroll
  for (int t = 0; t < 4; ++t) wf1[t] = *reinterpret_cast<const bf16x8*>(p1 + t * 8);
  const ushort* p2 = w2L + l * 80;
#pragma unroll
  for (int t = 0; t < 10; ++t) wf2[t] = *reinterpret_cast<const bf16x8*>(p2 + t * 8);
  f32x4 b2a = *reinterpret_cast<const f32x4*>(b2L + l * 8);
  const float b2t4 = b2L[l * 8 + 4];
  const float wps = wp[0], bps = bp[0];

#pragma unroll
  for (int mt = 0; mt < 4; ++mt) {
    const int px0 = mt * 16;

    // conv1 B-frag (pixel patches): B[k=hi*8+j][col=lo];
    // hi<3: taps (ky=hi, kx=j<3); hi==3,j==0: 1.0 (bias input)
    uint4 bw = {0u, 0u, 0u, 0u};
    if (hi < 3) {
      const float* row = &xg_s[1 + hi][px0 + lo + 1];
      bw.x = ((unsigned)f2bf(row[1]) << 16) | (unsigned)f2bf(row[0]);
      bw.y = (unsigned)f2bf(row[2]);
    } else {
      bw.x = 0x3F80u;
    }
    bf16x8 bpx = __builtin_bit_cast(bf16x8, bw);

    // conv1 swapped: A = weights, B = pixels. C_t[m=ch-sub][n=px].
    f32x4 zero = {0.f, 0.f, 0.f, 0.f};
    f32x4 h0 = __builtin_amdgcn_mfma_f32_16x16x32_bf16(wf1[0], bpx, zero, 0, 0, 0);
    f32x4 h1 = __builtin_amdgcn_mfma_f32_16x16x32_bf16(wf1[1], bpx, zero, 0, 0, 0);
    f32x4 h2 = __builtin_amdgcn_mfma_f32_16x16x32_bf16(wf1[2], bpx, zero, 0, 0, 0);
    f32x4 h3 = __builtin_amdgcn_mfma_f32_16x16x32_bf16(wf1[3], bpx, zero, 0, 0, 0);

    // ReLU + round-half-up + pack pairs via v_perm: word = (bf(b)<<16)|bf(a)
    auto rp = [](float a, float bb) -> unsigned {
      unsigned ua = __builtin_bit_cast(unsigned, fmaxf(a, 0.0f)) + 0x8000u;
      unsigned ub = __builtin_bit_cast(unsigned, fmaxf(bb, 0.0f)) + 0x8000u;
      return __builtin_amdgcn_perm(ub, ua, 0x07060302u);
    };
    uint4 aw, aw2;
    aw.x  = rp(h0[0], h0[1]); aw.y  = rp(h0[2], h0[3]);
    aw.z  = rp(h1[0], h1[1]); aw.w  = rp(h1[2], h1[3]);
    aw2.x = rp(h2[0], h2[1]); aw2.y = rp(h2[2], h2[3]);
    aw2.z = rp(h3[0], h3[1]); aw2.w = rp(h3[2], h3[3]);
    bf16x8 a2a = __builtin_bit_cast(bf16x8, aw);
    bf16x8 a2b = __builtin_bit_cast(bf16x8, aw2);

    // conv2: A from registers, acc init = b2*log2e, 10 MFMAs, exp -> e LDS
#pragma unroll
    for (int t = 0; t < 5; ++t) {
      float bini = (t < 4) ? b2a[t] : b2t4;
      f32x4 acc = {bini, bini, bini, bini};
      acc = __builtin_amdgcn_mfma_f32_16x16x32_bf16(a2a, wf2[2 * t], acc, 0, 0, 0);
      acc = __builtin_amdgcn_mfma_f32_16x16x32_bf16(a2b, wf2[2 * t + 1], acc, 0, 0, 0);
      int ch = t * 16 + lo;
      bool live = (ch < 75);
      if (live) {
#pragma unroll
        for (int r = 0; r < 4; ++r)
          e_s[(hi * 4 + r) * ES + ch] = EXP2(acc[r]);   // row = pixel, col = out-ch
      }
    }

    // epilogue: lane -> (px, v); e slot = kk*3+v directly
    const int epx = l >> 2, ev = l & 3;
    if (ev < 3) {
      const float* erow = e_s + epx * ES + ev;
      const float* nb = &xg_s[0][px0 + epx];
      float n0 = 0.f, n1 = 0.f, d0 = 0.f, d1 = 0.f;
#pragma unroll
      for (int kk = 0; kk < 25; ++kk) {
        int dy = kk / 5, dx = kk - dy * 5;
        float e = erow[3 * kk];
        float nv = nb[dy * XGS + dx];
        if (kk & 1) { n1 = fmaf(e, nv, n1); d1 += e; }
        else        { n0 = fmaf(e, nv, n0); d0 += e; }
      }
      float o = (n0 + n1) * __builtin_amdgcn_rcpf(d0 + d1) * wps + bps;
      int wg = wb + px0 + epx;
      float* op = out + (size_t)b * 3 * OPL + (size_t)h * OW + wg * 3 + ev;
      op[0] = o;
      op[OPL] = o;
      op[2 * (size_t)OPL] = o;
    }
  }
}

// Fallback (ws too small; not expected): fused per-pixel fp32 kernel.
__global__ __launch_bounds__(256) void carafe_fused_fallback(
    const float* __restrict__ x,
    const float* __restrict__ w1, const float* __restrict__ b1,
    const float* __restrict__ w2, const float* __restrict__ b2,
    const float* __restrict__ wp, const float* __restrict__ bp,
    float* __restrict__ out) {
  int idx = blockIdx.x * 256 + threadIdx.x;
  int b = idx >> 18;
  int hw = idx & (HW - 1);
  int h = hw >> 9;
  int w = hw & (WW - 1);
  float xw[5][5];
#pragma unroll
  for (int dy = 0; dy < 5; ++dy) {
    int y = h + dy - 2;
#pragma unroll
    for (int dx = 0; dx < 5; ++dx) {
      int xc = w + dx - 2;
      float v = 0.0f;
      if ((unsigned)y < (unsigned)HH && (unsigned)xc < (unsigned)WW) {
        const float* xb = x + (size_t)b * 3 * HW + y * WW + xc;
        v = (xb[0] + xb[HW] + xb[2 * HW]) * (1.0f / 3.0f);
      }
      xw[dy][dx] = v;
    }
  }
  float hb[64];
#pragma unroll
  for (int c = 0; c < 64; ++c) {
    float acc = b1[c];
#pragma unroll
    for (int ky = 0; ky < 3; ++ky)
#pragma unroll
      for (int kx = 0; kx < 3; ++kx)
        acc = fmaf(xw[1 + ky][1 + kx], w1[c * 9 + ky * 3 + kx], acc);
    hb[c] = fmaxf(acc, 0.0f);
  }
  float accv[3] = {0.f, 0.f, 0.f}, sumv[3] = {0.f, 0.f, 0.f};
#pragma unroll
  for (int kk = 0; kk < 25; ++kk) {
    float nv = xw[kk / 5][kk % 5];
#pragma unroll
    for (int v = 0; v < 3; ++v) {
      int ch = kk * 3 + v;
      float lg = b2[ch];
      const float* wrow = w2 + (size_t)ch * 64;
#pragma unroll
      for (int c = 0; c < 64; ++c) lg = fmaf(hb[c], wrow[c], lg);
      float e = __expf(lg);
      sumv[v] += e;
      accv[v] = fmaf(e, nv, accv[v]);
    }
  }
#pragma unroll
  for (int v = 0; v < 3; ++v) {
    float o = (accv[v] / sumv[v]) * wp[0] + bp[0];
    size_t base = (size_t)h * OW + (size_t)w * 3 + v;
#pragma unroll
    for (int c = 0; c < 3; ++c) out[(size_t)(b * 3 + c) * OPL + base] = o;
  }
}

extern "C" void kernel_launch(void* const* d_in, const int* in_sizes, int n_in,
                              void* d_out, int out_size, void* d_ws, size_t ws_size,
                              hipStream_t stream) {
  const float* x  = (const float*)d_in[0];
  const float* w1 = (const float*)d_in[1];
  const float* b1 = (const float*)d_in[2];
  const float* w2 = (const float*)d_in[3];
  const float* b2 = (const float*)d_in[4];
  const float* wp = (const float*)d_in[5];
  const float* bp = (const float*)d_in[6];
  float* out = (float*)d_out;

  const size_t need = (W1L_ELEMS + W2L_ELEMS) * sizeof(ushort) + B2L_ELEMS * sizeof(float);
  if (ws_size >= need) {
    ushort* w1p = (ushort*)d_ws;
    ushort* w2p = w1p + W1L_ELEMS;
    float*  b2p = (float*)(w2p + W2L_ELEMS);
    const int prep_total = W1L_ELEMS + W2L_ELEMS + B2L_ELEMS;
    prep_weights<<<(prep_total + 255) / 256, 256, 0, stream>>>(w1, b1, w2, b2, w1p, w2p, b2p);
    carafe_mfma<<<BB * HW / PXB, 64, 0, stream>>>(x, w1p, w2p, b2p, wp, bp, out);
  } else {
    carafe_fused_fallback<<<BB * HW / 256, 256, 0, stream>>>(x, w1, b1, w2, b2, wp, bp, out);
  }
}